// Round 1
// baseline (321.751 us; speedup 1.0000x reference)
//
#include <hip/hip_runtime.h>

#define N 4096            // row length
#define NEG_BIG -9999999.9f
#define CAP 256           // candidate buffer capacity per row
#define RPB 4             // rows per (persistent) block

// LDS-only barrier: drains lgkmcnt (LDS ops) but NOT vmcnt, so prefetched
// global loads stay in flight across the barrier. __syncthreads() would
// emit s_waitcnt vmcnt(0) before s_barrier and kill the cross-row prefetch.
__device__ __forceinline__ void bar_lds() {
    asm volatile("s_waitcnt lgkmcnt(0)" ::: "memory");
    __builtin_amdgcn_s_barrier();
    asm volatile("" ::: "memory");   // block hoisting LDS reads above barrier
}

// One row of work for this block. R is the compile-time row index within the
// block (0..RPB-1) so the double-buffer parity (R&1) is static -> registers,
// not scratch. XC/MC hold the (already issued) loads for THIS row; we issue
// the next row's loads into XN/MN before entering the serial tail so the
// tail hides the next row's HBM latency.
template<int R>
__device__ __forceinline__ void row_body(
    const float* __restrict__ x, const float* __restrict__ m,
    float* __restrict__ out, int row0, int rows,
    int lane, int wave, size_t halfoff,
    float4 (&XC)[8], float4 (&MC)[8],
    float4 (&XN)[8], float4 (&MN)[8],
    float (&smax)[2], float2 (&sparts)[2][2],
    float (&cand)[2][CAP], int (&cnt2)[2])
{
    const int row = row0 + R;
    if (row >= rows) return;                     // block-uniform

    constexpr int P = R & 1;                     // this row's LDS parity
    constexpr int Q = (R + 1) & 1;               // next row's LDS parity

    // z = (mask ? x : NEG_BIG) * 2   (/(1-TEMP), TEMP=0.5)
    float z[32];
    float rmax = -3.0e38f;
#pragma unroll
    for (int j = 0; j < 8; ++j) {
        float4 xv = XC[j];
        float4 mv = MC[j];
        float z0 = (mv.x != 0.0f ? xv.x : NEG_BIG) * 2.0f;
        float z1 = (mv.y != 0.0f ? xv.y : NEG_BIG) * 2.0f;
        float z2 = (mv.z != 0.0f ? xv.z : NEG_BIG) * 2.0f;
        float z3 = (mv.w != 0.0f ? xv.w : NEG_BIG) * 2.0f;
        z[4 * j + 0] = z0;
        z[4 * j + 1] = z1;
        z[4 * j + 2] = z2;
        z[4 * j + 3] = z3;
        rmax = fmaxf(rmax, fmaxf(fmaxf(z0, z1), fmaxf(z2, z3)));
    }

    // Prefetch next row into the other register buffer. Issued BEFORE the
    // reduce/barriers/Newton/store tail; the lgkm-only barriers below leave
    // these loads in flight until the next row_body consumes them.
    if (R + 1 < RPB && row + 1 < rows) {
        const float4* __restrict__ xr = (const float4*)x + (size_t)(row + 1) * (N / 4) + halfoff;
        const float4* __restrict__ mr = (const float4*)m + (size_t)(row + 1) * (N / 4) + halfoff;
#pragma unroll
        for (int j = 0; j < 8; ++j) {
            XN[j] = xr[j * 64 + lane];
            MN[j] = mr[j * 64 + lane];
        }
    }

    // Wave-wide max butterfly, then cross-wave combine via LDS.
#pragma unroll
    for (int k = 32; k >= 1; k >>= 1)
        rmax = fmaxf(rmax, __shfl_xor(rmax, k, 64));
    if (lane == 0) smax[wave] = rmax;
    bar_lds();                                   // barrier1: smax + cnt2[P] visible
    rmax = fmaxf(smax[0], smax[1]);

    // Append candidates w = z - rmax with w > -1 (support must lie here,
    // since sum_support(z - tau) = 1 implies tau >= rmax - 1).
    const float thr0 = rmax - 1.0f;
#pragma unroll
    for (int i = 0; i < 32; ++i) {
        if (z[i] > thr0) {
            int idx = atomicAdd(&cnt2[P], 1);
            if (idx < CAP) cand[P][idx] = z[i] - rmax;
        }
    }
    // Reset NEXT row's counter here: ordered after row R-1's K-read (which
    // completed before barrier1 of this row) and before row R+1's appends
    // (which start after its own barrier1 > this row's barrier2).
    if (threadIdx.x == 0) cnt2[Q] = 0;
    bar_lds();                                   // barrier2: appends + reset visible

    const int K = cnt2[P];                       // block-uniform
    float u = -1.0f;                             // solve sum max(w-u,0)=1
    if (K <= CAP) {
        // Tiny-set Newton, identical on every lane (LDS broadcasts).
        for (int it = 0; it < 32; ++it) {
            float s = 0.0f, c = 0.0f;
            for (int j = 0; j < K; ++j) {
                float v = cand[P][j] - u;
                if (v > 0.0f) { s += v; c += 1.0f; }
            }
            float un = u + (s - 1.0f) / c;       // monotone non-decreasing
            if (!(un > u)) break;                // exact fixed point
            u = un;
        }
    } else {
        // Fallback over the full row (e.g. all-masked: all w == 0).
        // K is block-uniform -> both waves take this branch; u sequence is
        // identical on both waves -> the break is block-uniform.
        int parity = 0;
        for (int it = 0; it < 32; ++it) {
            float s = 0.0f, c = 0.0f;
#pragma unroll
            for (int i = 0; i < 32; ++i) {
                float v = (z[i] - rmax) - u;
                if (v > 0.0f) { s += v; c += 1.0f; }
            }
#pragma unroll
            for (int k = 32; k >= 1; k >>= 1) {
                s += __shfl_xor(s, k, 64);
                c += __shfl_xor(c, k, 64);
            }
            if (lane == 0) sparts[parity][wave] = make_float2(s, c);
            bar_lds();
            float2 p0 = sparts[parity][0];
            float2 p1 = sparts[parity][1];
            float S = p0.x + p1.x;
            float C = p0.y + p1.y;
            float un = u + (S - 1.0f) / C;
            parity ^= 1;                         // double-buffer: no 2nd barrier
            if (!(un > u)) break;
            u = un;
        }
    }

    // All-masked row: reference multiplies by mask -> exact zeros.
    const float live = (rmax == NEG_BIG * 2.0f) ? 0.0f : 1.0f;
    const float thr  = rmax + u;                 // = tau

    float4* __restrict__ outr = (float4*)out + (size_t)row * (N / 4) + halfoff;
#pragma unroll
    for (int j = 0; j < 8; ++j) {
        float4 o;
        o.x = fmaxf(z[4 * j + 0] - thr, 0.0f) * live;
        o.y = fmaxf(z[4 * j + 1] - thr, 0.0f) * live;
        o.z = fmaxf(z[4 * j + 2] - thr, 0.0f) * live;
        o.w = fmaxf(z[4 * j + 3] - thr, 0.0f) * live;
        outr[j * 64 + lane] = o;
    }
}

// Persistent 4-row blocks, 2 waves (128 thr) per row, 32 elems/lane.
// ~108 live VGPRs (z[32] + 64-reg prefetch) -> 4 waves/SIMD tier, no spill.
// NOTE: no min-waves launch-bound -- earlier rounds showed (128,6)/(256,4)
// made the allocator under-allocate and spill the live z array.
__global__ __launch_bounds__(128)
void sparsemax_kernel(const float* __restrict__ x,
                      const float* __restrict__ m,
                      float* __restrict__ out,
                      int rows)
{
    const int lane = threadIdx.x & 63;
    const int wave = threadIdx.x >> 6;           // 0 or 1
    const int row0 = blockIdx.x * RPB;

    __shared__ float  smax[2];
    __shared__ float2 sparts[2][2];              // [parity][wave] fallback partials
    __shared__ float  cand[2][CAP];              // [row parity][.]  w = z - rmax
    __shared__ int    cnt2[2];                   // [row parity]
    if (threadIdx.x == 0) { cnt2[0] = 0; cnt2[1] = 0; }

    // Each wave owns half the row: 2048 elems = 512 float4, lane-strided.
    const size_t halfoff = (size_t)wave * (N / 8);

    float4 xa[8], ma[8], xb[8], mb[8];
    if (row0 < rows) {
        const float4* __restrict__ xr = (const float4*)x + (size_t)row0 * (N / 4) + halfoff;
        const float4* __restrict__ mr = (const float4*)m + (size_t)row0 * (N / 4) + halfoff;
#pragma unroll
        for (int j = 0; j < 8; ++j) {
            xa[j] = xr[j * 64 + lane];
            ma[j] = mr[j * 64 + lane];
        }
    }

    row_body<0>(x, m, out, row0, rows, lane, wave, halfoff, xa, ma, xb, mb, smax, sparts, cand, cnt2);
    row_body<1>(x, m, out, row0, rows, lane, wave, halfoff, xb, mb, xa, ma, smax, sparts, cand, cnt2);
    row_body<2>(x, m, out, row0, rows, lane, wave, halfoff, xa, ma, xb, mb, smax, sparts, cand, cnt2);
    row_body<3>(x, m, out, row0, rows, lane, wave, halfoff, xb, mb, xa, ma, smax, sparts, cand, cnt2);
}

extern "C" void kernel_launch(void* const* d_in, const int* in_sizes, int n_in,
                              void* d_out, int out_size, void* d_ws, size_t ws_size,
                              hipStream_t stream) {
    const float* x = (const float*)d_in[0];
    const float* m = (const float*)d_in[1];
    float* out = (float*)d_out;
    const int rows = in_sizes[0] / N;             // 8192
    const int nblk = (rows + RPB - 1) / RPB;      // 2048 persistent blocks
    sparsemax_kernel<<<nblk, 128, 0, stream>>>(x, m, out, rows);
}

// Round 2
// 315.364 us; speedup vs baseline: 1.0203x; 1.0203x over previous
//
#include <hip/hip_runtime.h>

#define N 4096            // row length
#define NEG_BIG -9999999.9f
#define CAP 256           // candidate buffer capacity per row

// v2 "max TLP x MLP" decisive experiment:
//  - ONE WAVE per row (64-thr blocks): zero barriers, zero cross-wave sync.
//    Single-wave DS program order makes cnt-reset / atomics / cand reads
//    safe without s_barrier (all lanes execute one instruction stream).
//  - grid-stride over 2 rows/block, 4096 blocks -> up to 16 resident
//    1-wave blocks per CU (if VGPR <= 128), 16 independent row streams
//    staggered per CU vs ~7 coupled 2-wave rows before.
//  - deep load bursts: 2 batches of 16 KB (8 x-float4 + 8 m-float4 issued
//    back-to-back) -> ~16 KB/wave in flight during load phase.
//  - short tail: per-lane candidate pack into STATIC regs (no runtime
//    indexing -> no scratch), ONE LDS atomic per lane, Newton on <=8
//    broadcast-loaded register candidates (sentinel -2.0f, valid since
//    u >= -1 always). LDS-loop and full-row butterfly fallbacks kept for
//    rare fat rows / all-masked rows.
__global__ __launch_bounds__(64)
void sparsemax_kernel(const float* __restrict__ x,
                      const float* __restrict__ m,
                      float* __restrict__ out,
                      int rows)
{
    const int lane = (int)threadIdx.x;    // 0..63, one full wave

    __shared__ float cand[CAP];
    __shared__ int   cnt;

    for (int row = blockIdx.x; row < rows; row += gridDim.x) {

        if (lane == 0) cnt = 0;           // same wave: ordered before atomics

        const size_t base = (size_t)row * (N / 4);
        const float4* __restrict__ xr = (const float4*)x + base;
        const float4* __restrict__ mr = (const float4*)m + base;

        float z[64];
        float rmax = -3.0e38f;

        // ---- batch A: float4 indices 0..511 (elements 0..2047)
        {
            float4 xv[8], mv[8];
#pragma unroll
            for (int j = 0; j < 8; ++j) xv[j] = xr[j * 64 + lane];
#pragma unroll
            for (int j = 0; j < 8; ++j) mv[j] = mr[j * 64 + lane];
#pragma unroll
            for (int j = 0; j < 8; ++j) {
                float z0 = (mv[j].x != 0.0f ? xv[j].x : NEG_BIG) * 2.0f;
                float z1 = (mv[j].y != 0.0f ? xv[j].y : NEG_BIG) * 2.0f;
                float z2 = (mv[j].z != 0.0f ? xv[j].z : NEG_BIG) * 2.0f;
                float z3 = (mv[j].w != 0.0f ? xv[j].w : NEG_BIG) * 2.0f;
                z[4 * j + 0] = z0;
                z[4 * j + 1] = z1;
                z[4 * j + 2] = z2;
                z[4 * j + 3] = z3;
                rmax = fmaxf(rmax, fmaxf(fmaxf(z0, z1), fmaxf(z2, z3)));
            }
        }
        // ---- batch B: float4 indices 512..1023 (elements 2048..4095)
        {
            float4 xv[8], mv[8];
#pragma unroll
            for (int j = 0; j < 8; ++j) xv[j] = xr[(8 + j) * 64 + lane];
#pragma unroll
            for (int j = 0; j < 8; ++j) mv[j] = mr[(8 + j) * 64 + lane];
#pragma unroll
            for (int j = 0; j < 8; ++j) {
                float z0 = (mv[j].x != 0.0f ? xv[j].x : NEG_BIG) * 2.0f;
                float z1 = (mv[j].y != 0.0f ? xv[j].y : NEG_BIG) * 2.0f;
                float z2 = (mv[j].z != 0.0f ? xv[j].z : NEG_BIG) * 2.0f;
                float z3 = (mv[j].w != 0.0f ? xv[j].w : NEG_BIG) * 2.0f;
                z[32 + 4 * j + 0] = z0;
                z[32 + 4 * j + 1] = z1;
                z[32 + 4 * j + 2] = z2;
                z[32 + 4 * j + 3] = z3;
                rmax = fmaxf(rmax, fmaxf(fmaxf(z0, z1), fmaxf(z2, z3)));
            }
        }

        // Wave-wide max butterfly: whole row lives in this wave.
#pragma unroll
        for (int k = 32; k >= 1; k >>= 1)
            rmax = fmaxf(rmax, __shfl_xor(rmax, k, 64));

        // Per-lane candidate pack: z > rmax-1 (support superset, since
        // sum_support(z - tau) = 1 implies tau >= rmax - 1). Static regs
        // only -- runtime-indexed arrays would go to scratch (rule #20).
        const float thr0 = rmax - 1.0f;
        float lc0 = 0.0f, lc1 = 0.0f, lc2 = 0.0f, lc3 = 0.0f;
        int lcnt = 0;
#pragma unroll
        for (int i = 0; i < 64; ++i) {
            if (z[i] > thr0) {
                float w = z[i] - rmax;
                lc0 = (lcnt == 0) ? w : lc0;
                lc1 = (lcnt == 1) ? w : lc1;
                lc2 = (lcnt == 2) ? w : lc2;
                lc3 = (lcnt == 3) ? w : lc3;
                ++lcnt;
            }
        }
        // One atomic per lane with candidates; stores ordered before the
        // cnt read below by same-wave DS program order.
        int basei = 0;
        if (lcnt > 0) basei = atomicAdd(&cnt, lcnt);
        if (lcnt > 0 && basei + 0 < CAP) cand[basei + 0] = lc0;
        if (lcnt > 1 && basei + 1 < CAP) cand[basei + 1] = lc1;
        if (lcnt > 2 && basei + 2 < CAP) cand[basei + 2] = lc2;
        if (lcnt > 3 && basei + 3 < CAP) cand[basei + 3] = lc3;

        const bool ovf = __any(lcnt > 4); // dropped candidates -> cand invalid
        const int  K   = cnt;             // wave-uniform
        float u = -1.0f;                  // solve sum max(w - u, 0) = 1

        if (!ovf && K <= 8) {
            // Broadcast candidates to registers; sentinel -2.0f is never
            // active since u >= -1 throughout (v = -2 - u <= -1 < 0).
            float c0 = (0 < K) ? cand[0] : -2.0f;
            float c1 = (1 < K) ? cand[1] : -2.0f;
            float c2 = (2 < K) ? cand[2] : -2.0f;
            float c3 = (3 < K) ? cand[3] : -2.0f;
            float c4 = (4 < K) ? cand[4] : -2.0f;
            float c5 = (5 < K) ? cand[5] : -2.0f;
            float c6 = (6 < K) ? cand[6] : -2.0f;
            float c7 = (7 < K) ? cand[7] : -2.0f;
            for (int it = 0; it < 32; ++it) {
                float s = 0.0f, c = 0.0f;
#define SPMAX_ACC(cc) { float v = (cc) - u; if (v > 0.0f) { s += v; c += 1.0f; } }
                SPMAX_ACC(c0) SPMAX_ACC(c1) SPMAX_ACC(c2) SPMAX_ACC(c3)
                SPMAX_ACC(c4) SPMAX_ACC(c5) SPMAX_ACC(c6) SPMAX_ACC(c7)
#undef SPMAX_ACC
                float un = u + (s - 1.0f) / c;   // monotone non-decreasing
                if (!(un > u)) break;            // exact fixed point
                u = un;
            }
        } else if (!ovf && K <= CAP) {
            // Fat row: Newton over the LDS candidate list.
            for (int it = 0; it < 32; ++it) {
                float s = 0.0f, c = 0.0f;
                for (int j = 0; j < K; ++j) {
                    float v = cand[j] - u;
                    if (v > 0.0f) { s += v; c += 1.0f; }
                }
                float un = u + (s - 1.0f) / c;
                if (!(un > u)) break;
                u = un;
            }
        } else {
            // Overflow (e.g. all-masked: every w == 0): full-row Newton with
            // butterfly reductions. Wave-uniform break (all lanes same S,C).
            for (int it = 0; it < 32; ++it) {
                float s = 0.0f, c = 0.0f;
#pragma unroll
                for (int i = 0; i < 64; ++i) {
                    float v = (z[i] - rmax) - u;
                    if (v > 0.0f) { s += v; c += 1.0f; }
                }
#pragma unroll
                for (int k = 32; k >= 1; k >>= 1) {
                    s += __shfl_xor(s, k, 64);
                    c += __shfl_xor(c, k, 64);
                }
                float un = u + (s - 1.0f) / c;
                if (!(un > u)) break;
                u = un;
            }
        }

        // All-masked row: reference multiplies by mask -> exact zeros.
        const float live = (rmax == NEG_BIG * 2.0f) ? 0.0f : 1.0f;
        const float thr  = rmax + u;              // = tau

        float4* __restrict__ outr = (float4*)out + base;
#pragma unroll
        for (int j = 0; j < 16; ++j) {
            float4 o;
            o.x = fmaxf(z[4 * j + 0] - thr, 0.0f) * live;
            o.y = fmaxf(z[4 * j + 1] - thr, 0.0f) * live;
            o.z = fmaxf(z[4 * j + 2] - thr, 0.0f) * live;
            o.w = fmaxf(z[4 * j + 3] - thr, 0.0f) * live;
            outr[j * 64 + lane] = o;
        }
    }
}

extern "C" void kernel_launch(void* const* d_in, const int* in_sizes, int n_in,
                              void* d_out, int out_size, void* d_ws, size_t ws_size,
                              hipStream_t stream) {
    const float* x = (const float*)d_in[0];
    const float* m = (const float*)d_in[1];
    float* out = (float*)d_out;
    const int rows = in_sizes[0] / N;             // 8192
    const int nblk = 4096;                        // 2 rows/block grid-stride;
                                                  // 16 blocks/CU resident cap
    sparsemax_kernel<<<nblk, 64, 0, stream>>>(x, m, out, rows);
}